// Round 14
// baseline (494.109 us; speedup 1.0000x reference)
//
#include <hip/hip_runtime.h>

// N=32, C=2, H=512, W=512, NO_STEPS=16
#define SN 32
#define SH 512
#define SW 512
#define SHW (SH * SW)        // 262144
#define SIMG (2 * SHW)       // 524288
#define STOTAL (SN * SIMG)   // 16,777,216 elems per field (64 MB)
#define SCALE (1.0f / 65536.0f)   // power of 2 -> scaling is exact
#define TPB 256
#define PAIRS_PER_IMG (SHW / 2)              // 131072 pixel-pairs
#define BLOCKS_PER_IMG (PAIRS_PER_IMG / TPB) // 512
#define GRID (SN * BLOCKS_PER_IMG)           // 16384

// fused geometry: 64x64 tile + 8px halo = 80x80 region in LDS
#define FT 64
#define FH 8
#define FR 80
#define FRS 81                // float2 row stride (AoS; round-10 verified)
#define FCPT 25               // cells per thread (6400/256)
#define FGRID (SN * 64)       // 2048 blocks

typedef float f4 __attribute__((ext_vector_type(4)));
typedef float f2 __attribute__((ext_vector_type(2)));
typedef f4 f4u __attribute__((aligned(8)));
typedef f2 f2u __attribute__((aligned(4)));

// nontemporal stores: inter-step buffers have no reuse within the writing
// step (read once next step, coalesced). Keeping them out of L2 leaves the
// XCD's 4MB exactly for {cur gather window 2MB + idg 2MB}.
__device__ __forceinline__ void nt_store_f4(f4 val, f4* p) {
    __builtin_nontemporal_store(val, p);
}
__device__ __forceinline__ void nt_store_f2(f2 val, f2* p) {
    __builtin_nontemporal_store(val, p);
}

// linear decode (fallback + last step): image n pinned to XCD b&7.
__device__ __forceinline__ void decode(int& n, int& bt) {
    int b = blockIdx.x;
    int q = b >> 3;
    n = (b & 7) + ((q >> 9) << 3);
    bt = ((q & 511) << 8) | threadIdx.x;
}

// Bilinear sample of interleaved float2 image (global). Ref semantics: clip
// BEFORE floor, border clamp. Paired 16B x-load covers both x-neighbors.
__device__ __forceinline__ float2 bilin(const float2* __restrict__ img,
                                        float gx, float gy) {
    float ix = ((gx + 1.0f) * (float)SW - 1.0f) * 0.5f;
    float iy = ((gy + 1.0f) * (float)SH - 1.0f) * 0.5f;
    ix = fminf(fmaxf(ix, 0.0f), (float)(SW - 1));
    iy = fminf(fmaxf(iy, 0.0f), (float)(SH - 1));
    float fx = floorf(ix), fy = floorf(iy);
    float wx = ix - fx, wy = iy - fy;
    int x0 = (int)fx, y0 = (int)fy;
    int y1 = min(y0 + 1, SH - 1);
    int xc = min(x0, SW - 2);
    bool xe = (x0 > SW - 2);
    f4u r0 = *(const f4u*)(img + y0 * SW + xc);
    f4u r1 = *(const f4u*)(img + y1 * SW + xc);
    float g00x = xe ? r0.z : r0.x, g00y = xe ? r0.w : r0.y;
    float g01x = r0.z,             g01y = r0.w;
    float g10x = xe ? r1.z : r1.x, g10y = xe ? r1.w : r1.y;
    float g11x = r1.z,             g11y = r1.w;
    float omwx = 1.0f - wx, omwy = 1.0f - wy;
    float sx = (g00x * omwx + g01x * wx) * omwy + (g10x * omwx + g11x * wx) * wy;
    float sy = (g00y * omwx + g01y * wx) * omwy + (g10y * omwx + g11y * wx) * wy;
    return make_float2(sx, sy);
}

// Planar-v bilinear, corners pre-scaled by SCALE (fallback path only).
__device__ __forceinline__ float2 bilinV(const float* __restrict__ c0,
                                         const float* __restrict__ c1,
                                         float gx, float gy) {
    float ix = ((gx + 1.0f) * (float)SW - 1.0f) * 0.5f;
    float iy = ((gy + 1.0f) * (float)SH - 1.0f) * 0.5f;
    ix = fminf(fmaxf(ix, 0.0f), (float)(SW - 1));
    iy = fminf(fmaxf(iy, 0.0f), (float)(SH - 1));
    float fx = floorf(ix), fy = floorf(iy);
    float wx = ix - fx, wy = iy - fy;
    int x0 = (int)fx, y0 = (int)fy;
    int y1 = min(y0 + 1, SH - 1);
    int xc = min(x0, SW - 2);
    bool xe = (x0 > SW - 2);
    f2u a0 = *(const f2u*)(c0 + y0 * SW + xc);
    f2u a1 = *(const f2u*)(c0 + y1 * SW + xc);
    f2u b0 = *(const f2u*)(c1 + y0 * SW + xc);
    f2u b1 = *(const f2u*)(c1 + y1 * SW + xc);
    float g00 = (xe ? a0.y : a0.x) * SCALE, g01 = a0.y * SCALE;
    float g10 = (xe ? a1.y : a1.x) * SCALE, g11 = a1.y * SCALE;
    float h00 = (xe ? b0.y : b0.x) * SCALE, h01 = b0.y * SCALE;
    float h10 = (xe ? b1.y : b1.x) * SCALE, h11 = b1.y * SCALE;
    float omwx = 1.0f - wx, omwy = 1.0f - wy;
    float s0 = (g00 * omwx + g01 * wx) * omwy + (g10 * omwx + g11 * wx) * wy;
    float s1 = (h00 * omwx + h01 * wx) * omwy + (h10 * omwx + h11 * wx) * wy;
    return make_float2(s0, s1);
}

// ---------------------------------------------------------------------------
// The NLEV-level loop body, specialized on INTERIOR (>=8px from image border:
// image clamps provably never bind for exact cells -> elided). Garbage halo
// cells may index OOB -> unsigned wrap -> DS OOB reads benign (validated
// rounds 10/12/13); garbage never propagates into the exact central region.
// ---------------------------------------------------------------------------
template<int NLEV, bool INTERIOR>
__device__ __forceinline__ void run_levels(
    float2* lds, const f2* idp, float2* nwr,
    int tid, int bx0, int by0)
{
    for (int k = 0; k < NLEV; ++k) {
        #pragma unroll
        for (int j = 0; j < FCPT; ++j) {
            int c = tid + j * TPB;
            int off = c + c / FR;              // own cell (stride 81)
            float2 wfv = lds[off];
            float gxx = idp[j].x + wfv.x;
            float gyy = idp[j].y + wfv.y;
            float ix = ((gxx + 1.0f) * (float)SW - 1.0f) * 0.5f;
            float iy = ((gyy + 1.0f) * (float)SH - 1.0f) * 0.5f;
            if constexpr (!INTERIOR) {
                ix = fminf(fmaxf(ix, 0.0f), (float)(SW - 1));
                iy = fminf(fmaxf(iy, 0.0f), (float)(SH - 1));
            }
            float fx = floorf(ix), fy = floorf(iy);
            float wx = ix - fx, wy = iy - fy;
            int x0 = (int)fx, y0 = (int)fy;
            int x1 = INTERIOR ? (x0 + 1) : min(x0 + 1, SW - 1);
            int y1 = INTERIOR ? (y0 + 1) : min(y0 + 1, SH - 1);
            unsigned rx0 = (unsigned)(x0 - bx0);
            unsigned rx1 = (unsigned)(x1 - bx0);
            unsigned ry0 = (unsigned)(y0 - by0);
            unsigned ry1 = (unsigned)(y1 - by0);
            unsigned rb0 = ry0 * (unsigned)FRS;
            unsigned rb1 = ry1 * (unsigned)FRS;
            float2 g00 = lds[rb0 + rx0], g01 = lds[rb0 + rx1];
            float2 g10 = lds[rb1 + rx0], g11 = lds[rb1 + rx1];
            float omwx = 1.0f - wx, omwy = 1.0f - wy;
            nwr[j].x = wfv.x + (g00.x * omwx + g01.x * wx) * omwy
                             + (g10.x * omwx + g11.x * wx) * wy;
            nwr[j].y = wfv.y + (g00.y * omwx + g01.y * wx) * omwy
                             + (g10.y * omwx + g11.y * wx) * wy;
        }
        __syncthreads();
        #pragma unroll
        for (int j = 0; j < FCPT; ++j) {
            int c = tid + j * TPB;
            lds[c + c / FR] = nwr[j];
        }
        __syncthreads();
    }
}

// ===========================================================================
// Fused NLEV squaring levels in LDS, 64x64 tile + 8 halo. Convexity:
// levels 1..6 reach 7.97 <= 8 (max|v|<=8); steps 7..8: 3+5 = 8 <= 8.
// Interior specialization via block-uniform runtime branch (round 13).
// ===========================================================================
template<int NLEV, bool SRCV>
__global__ __launch_bounds__(TPB) void svf_fusedK(
    const float* __restrict__ v,        // planar v (SRCV)
    const float2* __restrict__ src,     // interleaved field (!SRCV)
    const float2* __restrict__ idg,
    float2* __restrict__ dst)
{
    __shared__ float2 lds[FR * FRS];   // 51,840 B -> 3 blocks/CU
    const int b = blockIdx.x;
    const int q = b >> 3;                       // 0..255
    const int n = (b & 7) + ((q >> 6) << 3);    // image, pinned to XCD b&7
    const int t = q & 63;
    const int ty0 = (t >> 3) * FT, tx0 = (t & 7) * FT;
    const int bx0 = tx0 - FH, by0 = ty0 - FH;
    const int tid = threadIdx.x;
    const int tr = t >> 3, tc = t & 7;
    const bool interior = (tr >= 1) && (tr <= 6) && (tc >= 1) && (tc <= 6);

    f2 idp[FCPT];       // id cached across levels (static-indexed -> VGPRs)
    float2 nwr[FCPT];   // next-level staging

    // ---- load region into LDS + cache id ----
    if (interior) {
        #pragma unroll
        for (int j = 0; j < FCPT; ++j) {
            int c = tid + j * TPB;
            int ry = c / FR, rx = c - ry * FR;
            int gi = (by0 + ry) * SW + (bx0 + rx);
            float2 w0;
            if constexpr (SRCV) {
                const float* c0 = v + n * SIMG;
                w0 = make_float2(c0[gi] * SCALE, c0[SHW + gi] * SCALE);
            } else {
                w0 = src[n * SHW + gi];
            }
            lds[ry * FRS + rx] = w0;
            float2 idv = idg[gi];
            idp[j].x = idv.x; idp[j].y = idv.y;
        }
    } else {
        #pragma unroll
        for (int j = 0; j < FCPT; ++j) {
            int c = tid + j * TPB;
            int ry = c / FR, rx = c - ry * FR;
            int gx = min(max(bx0 + rx, 0), SW - 1);
            int gy = min(max(by0 + ry, 0), SH - 1);
            int gi = gy * SW + gx;
            float2 w0;
            if constexpr (SRCV) {
                const float* c0 = v + n * SIMG;
                w0 = make_float2(c0[gi] * SCALE, c0[SHW + gi] * SCALE);
            } else {
                w0 = src[n * SHW + gi];
            }
            lds[ry * FRS + rx] = w0;
            float2 idv = idg[gi];
            idp[j].x = idv.x; idp[j].y = idv.y;
        }
    }
    __syncthreads();

    // ---- NLEV bilinear levels (block-uniform branch) ----
    if (interior) run_levels<NLEV, true >(lds, idp, nwr, tid, bx0, by0);
    else          run_levels<NLEV, false>(lds, idp, nwr, tid, bx0, by0);

    // ---- write central 64x64 interleaved (nontemporal) ----
    float2* dimg = dst + n * SHW;
    #pragma unroll
    for (int j = 0; j < 16; ++j) {
        int c = tid + j * TPB;
        int oy = c >> 6, ox = c & 63;
        float2 w = lds[(oy + FH) * FRS + (ox + FH)];
        nt_store_f2(*(f2*)&w, (f2*)&dimg[(ty0 + oy) * SW + tx0 + ox]);
    }
}

// ===========================================================================
// Tiled global squaring step: 32x16-px tile per block; nontemporal output.
// ===========================================================================
__global__ void svf_step_t(const float2* __restrict__ cur,
                           const float2* __restrict__ idg,
                           float2* __restrict__ nxt) {
    int b = blockIdx.x;
    int q = b >> 3;
    int n = (b & 7) + ((q >> 9) << 3);     // image, pinned to XCD b&7
    int t = q & 511;                       // tile: 16 cols x 32 rows
    int tx0 = (t & 15) << 5;
    int ty0 = (t >> 4) << 4;
    int r  = threadIdx.x >> 4;
    int cp = threadIdx.x & 15;
    int bt = (ty0 + r) * (SW / 2) + (tx0 >> 1) + cp;

    const float2* img = cur + n * SHW;
    f4 wfp = ((const f4*)img)[bt];
    f4 idp = ((const f4*)idg)[bt];
    float2 sA = bilin(img, idp.x + wfp.x, idp.y + wfp.y);
    float2 sB = bilin(img, idp.z + wfp.z, idp.w + wfp.w);
    f4 o;
    o.x = wfp.x + sA.x; o.y = wfp.y + sA.y;
    o.z = wfp.z + sB.x; o.w = wfp.w + sB.y;
    nt_store_f4(o, (f4*)(nxt + n * SHW) + bt);
}

// linear step (fallback path)
__global__ void svf_step(const float2* __restrict__ cur,
                         const float2* __restrict__ idg,
                         float2* __restrict__ nxt) {
    int n, bt; decode(n, bt);
    const float2* img = cur + n * SHW;
    f4 wfp = ((const f4*)img)[bt];
    f4 idp = ((const f4*)idg)[bt];
    float2 sA = bilin(img, idp.x + wfp.x, idp.y + wfp.y);
    float2 sB = bilin(img, idp.z + wfp.z, idp.w + wfp.w);
    f4 o;
    o.x = wfp.x + sA.x; o.y = wfp.y + sA.y;
    o.z = wfp.z + sB.x; o.w = wfp.w + sB.y;
    nt_store_f4(o, (f4*)(nxt + n * SHW) + bt);
}

// fused step 16 + epilogue: src disjoint from out -> write planar warp_field
// AND transformation directly (nontemporal; outputs never re-read on device).
__global__ void svf_last_fused(const float2* __restrict__ cur,
                               const float2* __restrict__ idg,
                               float* __restrict__ out) {
    int n, bt; decode(n, bt);
    const float2* img = cur + n * SHW;
    f4 wfp = ((const f4*)img)[bt];
    f4 idp = ((const f4*)idg)[bt];
    float2 sA = bilin(img, idp.x + wfp.x, idp.y + wfp.y);
    float2 sB = bilin(img, idp.z + wfp.z, idp.w + wfp.w);
    float u0 = wfp.x + sA.x, w0 = wfp.y + sA.y;
    float u1 = wfp.z + sB.x, w1 = wfp.w + sB.y;
    int p = bt << 1;
    float* wfo = out + STOTAL + n * SIMG;
    f2 a; a.x = u0; a.y = u1; nt_store_f2(a, (f2*)(wfo + p));
    f2 b; b.x = w0; b.y = w1; nt_store_f2(b, (f2*)(wfo + SHW + p));
    float* tro = out + n * SIMG;
    f2 c; c.x = u0 + idp.x; c.y = u1 + idp.z; nt_store_f2(c, (f2*)(tro + p));
    f2 d; d.x = w0 + idp.y; d.y = w1 + idp.w; nt_store_f2(d, (f2*)(tro + SHW + p));
}

// ===========================================================================
// Fallback (no usable ws): verified round-5 multi-launch path.
// ===========================================================================
__global__ void svf_first(const float* __restrict__ v,
                          const float2* __restrict__ idg,
                          float2* __restrict__ nxt) {
    int n, bt; decode(n, bt);
    const float* c0 = v + n * SIMG;
    const float* c1 = c0 + SHW;
    int p = bt << 1;
    f2 u2 = *(const f2*)(c0 + p);
    f2 w2 = *(const f2*)(c1 + p);
    f4 idp = ((const f4*)idg)[bt];
    float uA = u2.x * SCALE, wA = w2.x * SCALE;
    float uB = u2.y * SCALE, wB = w2.y * SCALE;
    float2 sA = bilinV(c0, c1, idp.x + uA, idp.y + wA);
    float2 sB = bilinV(c0, c1, idp.z + uB, idp.w + wB);
    f4 o;
    o.x = uA + sA.x; o.y = wA + sA.y;
    o.z = uB + sB.x; o.w = wB + sB.y;
    nt_store_f4(o, (f4*)(nxt + n * SHW) + bt);
}

__global__ void svf_last_wf(const float2* __restrict__ cur,
                            const float2* __restrict__ idg,
                            float* __restrict__ wfout) {
    int n, bt; decode(n, bt);
    const float2* img = cur + n * SHW;
    f4 wfp = ((const f4*)img)[bt];
    f4 idp = ((const f4*)idg)[bt];
    float2 sA = bilin(img, idp.x + wfp.x, idp.y + wfp.y);
    float2 sB = bilin(img, idp.z + wfp.z, idp.w + wfp.w);
    int p = bt << 1;
    float* ob = wfout + n * SIMG;
    f2 a; a.x = wfp.x + sA.x; a.y = wfp.z + sB.x; *(f2*)(ob + p) = a;
    f2 b; b.x = wfp.y + sA.y; b.y = wfp.w + sB.y; *(f2*)(ob + SHW + p) = b;
}

__global__ void svf_final(const float* __restrict__ wf,
                          const float2* __restrict__ idg,
                          float* __restrict__ tr) {
    int n, bt; decode(n, bt);
    int p = bt << 1;
    f4 idp = ((const f4*)idg)[bt];
    const float* ib = wf + n * SIMG;
    float* ob = tr + n * SIMG;
    f2 u2 = *(const f2*)(ib + p);
    f2 w2 = *(const f2*)(ib + SHW + p);
    f2 c; c.x = u2.x + idp.x; c.y = u2.y + idp.z; *(f2*)(ob + p) = c;
    f2 d; d.x = w2.x + idp.y; d.y = w2.y + idp.w; *(f2*)(ob + SHW + p) = d;
}

extern "C" void kernel_launch(void* const* d_in, const int* in_sizes, int n_in,
                              void* d_out, int out_size, void* d_ws, size_t ws_size,
                              hipStream_t stream) {
    const float* v    = (const float*)d_in[0];
    const float2* idg = (const float2*)d_in[1];  // [1,H,W,2] = float2/pixel
    float* out = (float*)d_out;                  // [transformation | warp_field]

    const bool ws_ok = (d_ws != nullptr) && (ws_size >= (size_t)STOTAL * 4);

    if (ws_ok) {
        float2* W  = (float2*)d_ws;              // interleaved scratch
        float2* H2 = (float2*)(out + STOTAL);    // wf slot as scratch
        // steps 1..6 fused in LDS: v -> W (wf6)
        svf_fusedK<6, true><<<FGRID, TPB, 0, stream>>>(v, nullptr, idg, W);
        // steps 7..8 fused in LDS: W -> H2 (wf8)
        svf_fusedK<2, false><<<FGRID, TPB, 0, stream>>>(nullptr, W, idg, H2);
        // steps 9..15 (7 tiled passes): H2 -> W -> ... ends in W (wf15)
        const float2* cur = H2; float2* nxt = W;
        for (int s = 0; s < 7; ++s) {
            svf_step_t<<<GRID, TPB, 0, stream>>>(cur, idg, nxt);
            const float2* tt = nxt; nxt = (float2*)cur; cur = tt;
        }
        // step 16 + epilogue: reads W (disjoint from out) -> both halves
        svf_last_fused<<<GRID, TPB, 0, stream>>>(cur, idg, out);
    } else {
        float2* B0 = (float2*)out;
        float2* B1 = (float2*)(out + STOTAL);
        svf_first<<<GRID, TPB, 0, stream>>>(v, idg, B0);
        const float2* cur = B0; float2* nxt = B1;
        for (int s = 0; s < 14; ++s) {
            svf_step<<<GRID, TPB, 0, stream>>>(cur, idg, nxt);
            const float2* tt = nxt; nxt = (float2*)cur; cur = tt;
        }
        svf_last_wf<<<GRID, TPB, 0, stream>>>(cur, idg, out + STOTAL);
        svf_final<<<GRID, TPB, 0, stream>>>(out + STOTAL, idg, out);
    }
}

// Round 15
// 402.148 us; speedup vs baseline: 1.2287x; 1.2287x over previous
//
#include <hip/hip_runtime.h>

// N=32, C=2, H=512, W=512, NO_STEPS=16
#define SN 32
#define SH 512
#define SW 512
#define SHW (SH * SW)        // 262144
#define SIMG (2 * SHW)       // 524288
#define STOTAL (SN * SIMG)   // 16,777,216 elems per field (64 MB)
#define SCALE (1.0f / 65536.0f)   // power of 2 -> scaling is exact
#define TPB 256
#define PAIRS_PER_IMG (SHW / 2)              // 131072 pixel-pairs
#define BLOCKS_PER_IMG (PAIRS_PER_IMG / TPB) // 512
#define GRID (SN * BLOCKS_PER_IMG)           // 16384

// fused geometry: 64x64 tile + 8px halo = 80x80 region in LDS
#define FT 64
#define FH 8
#define FR 80
#define FRS 81                // float2 row stride (AoS; round-10 verified)
#define FCPT 25               // cells per thread (6400/256)
#define FGRID (SN * 64)       // 2048 blocks

typedef float f4 __attribute__((ext_vector_type(4)));
typedef float f2 __attribute__((ext_vector_type(2)));
typedef f4 f4u __attribute__((aligned(8)));
typedef f2 f2u __attribute__((aligned(4)));

// linear decode (fallback + last step): image n pinned to XCD b&7.
__device__ __forceinline__ void decode(int& n, int& bt) {
    int b = blockIdx.x;
    int q = b >> 3;
    n = (b & 7) + ((q >> 9) << 3);
    bt = ((q & 511) << 8) | threadIdx.x;
}

// Bilinear sample of interleaved float2 image (global). Ref semantics: clip
// BEFORE floor, border clamp. Paired 16B x-load covers both x-neighbors.
// NOTE (round 14 lesson): ping-pong writes MUST stay in L2 — they are the
// next step's gather source. Nontemporal stores here cost +90 µs.
__device__ __forceinline__ float2 bilin(const float2* __restrict__ img,
                                        float gx, float gy) {
    float ix = ((gx + 1.0f) * (float)SW - 1.0f) * 0.5f;
    float iy = ((gy + 1.0f) * (float)SH - 1.0f) * 0.5f;
    ix = fminf(fmaxf(ix, 0.0f), (float)(SW - 1));
    iy = fminf(fmaxf(iy, 0.0f), (float)(SH - 1));
    float fx = floorf(ix), fy = floorf(iy);
    float wx = ix - fx, wy = iy - fy;
    int x0 = (int)fx, y0 = (int)fy;
    int y1 = min(y0 + 1, SH - 1);
    int xc = min(x0, SW - 2);
    bool xe = (x0 > SW - 2);
    f4u r0 = *(const f4u*)(img + y0 * SW + xc);
    f4u r1 = *(const f4u*)(img + y1 * SW + xc);
    float g00x = xe ? r0.z : r0.x, g00y = xe ? r0.w : r0.y;
    float g01x = r0.z,             g01y = r0.w;
    float g10x = xe ? r1.z : r1.x, g10y = xe ? r1.w : r1.y;
    float g11x = r1.z,             g11y = r1.w;
    float omwx = 1.0f - wx, omwy = 1.0f - wy;
    float sx = (g00x * omwx + g01x * wx) * omwy + (g10x * omwx + g11x * wx) * wy;
    float sy = (g00y * omwx + g01y * wx) * omwy + (g10y * omwx + g11y * wx) * wy;
    return make_float2(sx, sy);
}

// Planar-v bilinear, corners pre-scaled by SCALE (fallback path only).
__device__ __forceinline__ float2 bilinV(const float* __restrict__ c0,
                                         const float* __restrict__ c1,
                                         float gx, float gy) {
    float ix = ((gx + 1.0f) * (float)SW - 1.0f) * 0.5f;
    float iy = ((gy + 1.0f) * (float)SH - 1.0f) * 0.5f;
    ix = fminf(fmaxf(ix, 0.0f), (float)(SW - 1));
    iy = fminf(fmaxf(iy, 0.0f), (float)(SH - 1));
    float fx = floorf(ix), fy = floorf(iy);
    float wx = ix - fx, wy = iy - fy;
    int x0 = (int)fx, y0 = (int)fy;
    int y1 = min(y0 + 1, SH - 1);
    int xc = min(x0, SW - 2);
    bool xe = (x0 > SW - 2);
    f2u a0 = *(const f2u*)(c0 + y0 * SW + xc);
    f2u a1 = *(const f2u*)(c0 + y1 * SW + xc);
    f2u b0 = *(const f2u*)(c1 + y0 * SW + xc);
    f2u b1 = *(const f2u*)(c1 + y1 * SW + xc);
    float g00 = (xe ? a0.y : a0.x) * SCALE, g01 = a0.y * SCALE;
    float g10 = (xe ? a1.y : a1.x) * SCALE, g11 = a1.y * SCALE;
    float h00 = (xe ? b0.y : b0.x) * SCALE, h01 = b0.y * SCALE;
    float h10 = (xe ? b1.y : b1.x) * SCALE, h11 = b1.y * SCALE;
    float omwx = 1.0f - wx, omwy = 1.0f - wy;
    float s0 = (g00 * omwx + g01 * wx) * omwy + (g10 * omwx + g11 * wx) * wy;
    float s1 = (h00 * omwx + h01 * wx) * omwy + (h10 * omwx + h11 * wx) * wy;
    return make_float2(s0, s1);
}

// ---------------------------------------------------------------------------
// The NLEV-level loop body, specialized on INTERIOR (>=8px from image border:
// image clamps provably never bind for exact cells -> elided). Garbage halo
// cells may index OOB -> unsigned wrap -> DS OOB reads benign (validated
// rounds 10/12/13); garbage never propagates into the exact central region.
// ---------------------------------------------------------------------------
template<int NLEV, bool INTERIOR>
__device__ __forceinline__ void run_levels(
    float2* lds, const f2* idp, float2* nwr,
    int tid, int bx0, int by0)
{
    for (int k = 0; k < NLEV; ++k) {
        #pragma unroll
        for (int j = 0; j < FCPT; ++j) {
            int c = tid + j * TPB;
            int off = c + c / FR;              // own cell (stride 81)
            float2 wfv = lds[off];
            float gxx = idp[j].x + wfv.x;
            float gyy = idp[j].y + wfv.y;
            float ix = ((gxx + 1.0f) * (float)SW - 1.0f) * 0.5f;
            float iy = ((gyy + 1.0f) * (float)SH - 1.0f) * 0.5f;
            if constexpr (!INTERIOR) {
                ix = fminf(fmaxf(ix, 0.0f), (float)(SW - 1));
                iy = fminf(fmaxf(iy, 0.0f), (float)(SH - 1));
            }
            float fx = floorf(ix), fy = floorf(iy);
            float wx = ix - fx, wy = iy - fy;
            int x0 = (int)fx, y0 = (int)fy;
            int x1 = INTERIOR ? (x0 + 1) : min(x0 + 1, SW - 1);
            int y1 = INTERIOR ? (y0 + 1) : min(y0 + 1, SH - 1);
            unsigned rx0 = (unsigned)(x0 - bx0);
            unsigned rx1 = (unsigned)(x1 - bx0);
            unsigned ry0 = (unsigned)(y0 - by0);
            unsigned ry1 = (unsigned)(y1 - by0);
            unsigned rb0 = ry0 * (unsigned)FRS;
            unsigned rb1 = ry1 * (unsigned)FRS;
            float2 g00 = lds[rb0 + rx0], g01 = lds[rb0 + rx1];
            float2 g10 = lds[rb1 + rx0], g11 = lds[rb1 + rx1];
            float omwx = 1.0f - wx, omwy = 1.0f - wy;
            nwr[j].x = wfv.x + (g00.x * omwx + g01.x * wx) * omwy
                             + (g10.x * omwx + g11.x * wx) * wy;
            nwr[j].y = wfv.y + (g00.y * omwx + g01.y * wx) * omwy
                             + (g10.y * omwx + g11.y * wx) * wy;
        }
        __syncthreads();
        #pragma unroll
        for (int j = 0; j < FCPT; ++j) {
            int c = tid + j * TPB;
            lds[c + c / FR] = nwr[j];
        }
        __syncthreads();
    }
}

// ===========================================================================
// Fused NLEV squaring levels in LDS, 64x64 tile + 8 halo. Convexity:
// levels 1..6 reach 7.97 <= 8 (max|v|<=8); steps 7..8: 3+5 = 8 <= 8.
// Interior specialization via block-uniform runtime branch (round 13).
// ===========================================================================
template<int NLEV, bool SRCV>
__global__ __launch_bounds__(TPB) void svf_fusedK(
    const float* __restrict__ v,        // planar v (SRCV)
    const float2* __restrict__ src,     // interleaved field (!SRCV)
    const float2* __restrict__ idg,
    float2* __restrict__ dst)
{
    __shared__ float2 lds[FR * FRS];   // 51,840 B -> 3 blocks/CU
    const int b = blockIdx.x;
    const int q = b >> 3;                       // 0..255
    const int n = (b & 7) + ((q >> 6) << 3);    // image, pinned to XCD b&7
    const int t = q & 63;
    const int ty0 = (t >> 3) * FT, tx0 = (t & 7) * FT;
    const int bx0 = tx0 - FH, by0 = ty0 - FH;
    const int tid = threadIdx.x;
    const int tr = t >> 3, tc = t & 7;
    const bool interior = (tr >= 1) && (tr <= 6) && (tc >= 1) && (tc <= 6);

    f2 idp[FCPT];       // id cached across levels (static-indexed -> VGPRs)
    float2 nwr[FCPT];   // next-level staging

    // ---- load region into LDS + cache id ----
    if (interior) {
        #pragma unroll
        for (int j = 0; j < FCPT; ++j) {
            int c = tid + j * TPB;
            int ry = c / FR, rx = c - ry * FR;
            int gi = (by0 + ry) * SW + (bx0 + rx);
            float2 w0;
            if constexpr (SRCV) {
                const float* c0 = v + n * SIMG;
                w0 = make_float2(c0[gi] * SCALE, c0[SHW + gi] * SCALE);
            } else {
                w0 = src[n * SHW + gi];
            }
            lds[ry * FRS + rx] = w0;
            float2 idv = idg[gi];
            idp[j].x = idv.x; idp[j].y = idv.y;
        }
    } else {
        #pragma unroll
        for (int j = 0; j < FCPT; ++j) {
            int c = tid + j * TPB;
            int ry = c / FR, rx = c - ry * FR;
            int gx = min(max(bx0 + rx, 0), SW - 1);
            int gy = min(max(by0 + ry, 0), SH - 1);
            int gi = gy * SW + gx;
            float2 w0;
            if constexpr (SRCV) {
                const float* c0 = v + n * SIMG;
                w0 = make_float2(c0[gi] * SCALE, c0[SHW + gi] * SCALE);
            } else {
                w0 = src[n * SHW + gi];
            }
            lds[ry * FRS + rx] = w0;
            float2 idv = idg[gi];
            idp[j].x = idv.x; idp[j].y = idv.y;
        }
    }
    __syncthreads();

    // ---- NLEV bilinear levels (block-uniform branch) ----
    if (interior) run_levels<NLEV, true >(lds, idp, nwr, tid, bx0, by0);
    else          run_levels<NLEV, false>(lds, idp, nwr, tid, bx0, by0);

    // ---- write central 64x64 interleaved ----
    float2* dimg = dst + n * SHW;
    #pragma unroll
    for (int j = 0; j < 16; ++j) {
        int c = tid + j * TPB;
        int oy = c >> 6, ox = c & 63;
        dimg[(ty0 + oy) * SW + tx0 + ox] = lds[(oy + FH) * FRS + (ox + FH)];
    }
}

// ===========================================================================
// Tiled global squaring step: 32x16-px tile per block.
// ===========================================================================
__global__ void svf_step_t(const float2* __restrict__ cur,
                           const float2* __restrict__ idg,
                           float2* __restrict__ nxt) {
    int b = blockIdx.x;
    int q = b >> 3;
    int n = (b & 7) + ((q >> 9) << 3);     // image, pinned to XCD b&7
    int t = q & 511;                       // tile: 16 cols x 32 rows
    int tx0 = (t & 15) << 5;
    int ty0 = (t >> 4) << 4;
    int r  = threadIdx.x >> 4;
    int cp = threadIdx.x & 15;
    int bt = (ty0 + r) * (SW / 2) + (tx0 >> 1) + cp;

    const float2* img = cur + n * SHW;
    f4 wfp = ((const f4*)img)[bt];
    f4 idp = ((const f4*)idg)[bt];
    float2 sA = bilin(img, idp.x + wfp.x, idp.y + wfp.y);
    float2 sB = bilin(img, idp.z + wfp.z, idp.w + wfp.w);
    f4 o;
    o.x = wfp.x + sA.x; o.y = wfp.y + sA.y;
    o.z = wfp.z + sB.x; o.w = wfp.w + sB.y;
    ((f4*)(nxt + n * SHW))[bt] = o;
}

// linear step (fallback path)
__global__ void svf_step(const float2* __restrict__ cur,
                         const float2* __restrict__ idg,
                         float2* __restrict__ nxt) {
    int n, bt; decode(n, bt);
    const float2* img = cur + n * SHW;
    f4 wfp = ((const f4*)img)[bt];
    f4 idp = ((const f4*)idg)[bt];
    float2 sA = bilin(img, idp.x + wfp.x, idp.y + wfp.y);
    float2 sB = bilin(img, idp.z + wfp.z, idp.w + wfp.w);
    f4 o;
    o.x = wfp.x + sA.x; o.y = wfp.y + sA.y;
    o.z = wfp.z + sB.x; o.w = wfp.w + sB.y;
    ((f4*)(nxt + n * SHW))[bt] = o;
}

// fused step 16 + epilogue: src disjoint from out -> write planar warp_field
// AND transformation directly.
__global__ void svf_last_fused(const float2* __restrict__ cur,
                               const float2* __restrict__ idg,
                               float* __restrict__ out) {
    int n, bt; decode(n, bt);
    const float2* img = cur + n * SHW;
    f4 wfp = ((const f4*)img)[bt];
    f4 idp = ((const f4*)idg)[bt];
    float2 sA = bilin(img, idp.x + wfp.x, idp.y + wfp.y);
    float2 sB = bilin(img, idp.z + wfp.z, idp.w + wfp.w);
    float u0 = wfp.x + sA.x, w0 = wfp.y + sA.y;
    float u1 = wfp.z + sB.x, w1 = wfp.w + sB.y;
    int p = bt << 1;
    float* wfo = out + STOTAL + n * SIMG;
    f2 a; a.x = u0; a.y = u1; *(f2*)(wfo + p) = a;
    f2 b; b.x = w0; b.y = w1; *(f2*)(wfo + SHW + p) = b;
    float* tro = out + n * SIMG;
    f2 c; c.x = u0 + idp.x; c.y = u1 + idp.z; *(f2*)(tro + p) = c;
    f2 d; d.x = w0 + idp.y; d.y = w1 + idp.w; *(f2*)(tro + SHW + p) = d;
}

// ===========================================================================
// Fallback (no usable ws): verified round-5 multi-launch path.
// ===========================================================================
__global__ void svf_first(const float* __restrict__ v,
                          const float2* __restrict__ idg,
                          float2* __restrict__ nxt) {
    int n, bt; decode(n, bt);
    const float* c0 = v + n * SIMG;
    const float* c1 = c0 + SHW;
    int p = bt << 1;
    f2 u2 = *(const f2*)(c0 + p);
    f2 w2 = *(const f2*)(c1 + p);
    f4 idp = ((const f4*)idg)[bt];
    float uA = u2.x * SCALE, wA = w2.x * SCALE;
    float uB = u2.y * SCALE, wB = w2.y * SCALE;
    float2 sA = bilinV(c0, c1, idp.x + uA, idp.y + wA);
    float2 sB = bilinV(c0, c1, idp.z + uB, idp.w + wB);
    f4 o;
    o.x = uA + sA.x; o.y = wA + sA.y;
    o.z = uB + sB.x; o.w = wB + sB.y;
    ((f4*)(nxt + n * SHW))[bt] = o;
}

__global__ void svf_last_wf(const float2* __restrict__ cur,
                            const float2* __restrict__ idg,
                            float* __restrict__ wfout) {
    int n, bt; decode(n, bt);
    const float2* img = cur + n * SHW;
    f4 wfp = ((const f4*)img)[bt];
    f4 idp = ((const f4*)idg)[bt];
    float2 sA = bilin(img, idp.x + wfp.x, idp.y + wfp.y);
    float2 sB = bilin(img, idp.z + wfp.z, idp.w + wfp.w);
    int p = bt << 1;
    float* ob = wfout + n * SIMG;
    f2 a; a.x = wfp.x + sA.x; a.y = wfp.z + sB.x; *(f2*)(ob + p) = a;
    f2 b; b.x = wfp.y + sA.y; b.y = wfp.w + sB.y; *(f2*)(ob + SHW + p) = b;
}

__global__ void svf_final(const float* __restrict__ wf,
                          const float2* __restrict__ idg,
                          float* __restrict__ tr) {
    int n, bt; decode(n, bt);
    int p = bt << 1;
    f4 idp = ((const f4*)idg)[bt];
    const float* ib = wf + n * SIMG;
    float* ob = tr + n * SIMG;
    f2 u2 = *(const f2*)(ib + p);
    f2 w2 = *(const f2*)(ib + SHW + p);
    f2 c; c.x = u2.x + idp.x; c.y = u2.y + idp.z; *(f2*)(ob + p) = c;
    f2 d; d.x = w2.x + idp.y; d.y = w2.y + idp.w; *(f2*)(ob + SHW + p) = d;
}

extern "C" void kernel_launch(void* const* d_in, const int* in_sizes, int n_in,
                              void* d_out, int out_size, void* d_ws, size_t ws_size,
                              hipStream_t stream) {
    const float* v    = (const float*)d_in[0];
    const float2* idg = (const float2*)d_in[1];  // [1,H,W,2] = float2/pixel
    float* out = (float*)d_out;                  // [transformation | warp_field]

    const bool ws_ok = (d_ws != nullptr) && (ws_size >= (size_t)STOTAL * 4);

    if (ws_ok) {
        float2* W  = (float2*)d_ws;              // interleaved scratch
        float2* H2 = (float2*)(out + STOTAL);    // wf slot as scratch
        // steps 1..6 fused in LDS: v -> W (wf6)
        svf_fusedK<6, true><<<FGRID, TPB, 0, stream>>>(v, nullptr, idg, W);
        // steps 7..8 fused in LDS: W -> H2 (wf8)
        svf_fusedK<2, false><<<FGRID, TPB, 0, stream>>>(nullptr, W, idg, H2);
        // steps 9..15 (7 tiled passes): H2 -> W -> ... ends in W (wf15)
        const float2* cur = H2; float2* nxt = W;
        for (int s = 0; s < 7; ++s) {
            svf_step_t<<<GRID, TPB, 0, stream>>>(cur, idg, nxt);
            const float2* tt = nxt; nxt = (float2*)cur; cur = tt;
        }
        // step 16 + epilogue: reads W (disjoint from out) -> both halves
        svf_last_fused<<<GRID, TPB, 0, stream>>>(cur, idg, out);
    } else {
        float2* B0 = (float2*)out;
        float2* B1 = (float2*)(out + STOTAL);
        svf_first<<<GRID, TPB, 0, stream>>>(v, idg, B0);
        const float2* cur = B0; float2* nxt = B1;
        for (int s = 0; s < 14; ++s) {
            svf_step<<<GRID, TPB, 0, stream>>>(cur, idg, nxt);
            const float2* tt = nxt; nxt = (float2*)cur; cur = tt;
        }
        svf_last_wf<<<GRID, TPB, 0, stream>>>(cur, idg, out + STOTAL);
        svf_final<<<GRID, TPB, 0, stream>>>(out + STOTAL, idg, out);
    }
}